// Round 1
// baseline (287.400 us; speedup 1.0000x reference)
//
#include <hip/hip_runtime.h>

typedef unsigned int u32;
typedef unsigned short u16;
typedef __attribute__((ext_vector_type(8))) short bf16x8;  // 8 bf16 = 4 VGPRs
typedef __attribute__((ext_vector_type(4))) float f32x4;

#define KN 8192
#define DD 256
#define HW 1024
#define NP 32768
#define SPLITS 2
#define KSPLIT 4096
#define BROW 256   // rows (z points) per block, resident
#define BCOL 256   // cols (codebook entries) per streamed tile
#define NTILES (KSPLIT / BCOL)   // 16

__device__ __forceinline__ u16 rne_bf16(float x) {
    u32 u = __float_as_uint(x);
    return (u16)((u + 0x7FFF + ((u >> 16) & 1)) >> 16);
}

__device__ __forceinline__ void glds16(const void* g, void* ldsbase) {
    __builtin_amdgcn_global_load_lds((const __attribute__((address_space(1))) u32*)g,
                                     (__attribute__((address_space(3))) u32*)ldsbase, 16, 0, 0);
}

// ---------------- merged prep: enorm | eT/eTf transpose | A build (unchanged) ----------------
__global__ void prep_kernel(const float* __restrict__ e, const float* __restrict__ z,
                            u16* __restrict__ eT, float* __restrict__ eTf,
                            float* __restrict__ e2f, u16* __restrict__ A) {
    const int t = threadIdx.x;
    const int bid = blockIdx.x;
    if (bid < 32) {
        int k = bid * 256 + t;
        float acc = 0.f;
#pragma unroll 8
        for (int d = 0; d < DD; ++d) {
            float v = e[(size_t)d * KN + k];
            acc = fmaf(v, v, acc);
        }
        e2f[k] = acc;
    } else if (bid < 544) {
        __shared__ float tt[64][65];
        const int b2 = bid - 32;
        const int kt = b2 & 127;     // 0..127
        const int dt = b2 >> 7;      // 0..3
        const float* ep = e + (size_t)(dt * 64) * KN + kt * 64;
        {
            int k = t & 63, d0 = t >> 6;
#pragma unroll
            for (int j = 0; j < 16; ++j) tt[d0 + j * 4][k] = ep[(size_t)(d0 + j * 4) * KN + k];
        }
        __syncthreads();
        int k = t >> 2, c0 = (t & 3) * 16;
        u16 hi[16];
        float fv[16];
#pragma unroll
        for (int j = 0; j < 16; ++j) {
            float v = tt[c0 + j][k];
            fv[j] = v;
            hi[j] = rne_bf16(v);
        }
        u16* rowp = eT + (size_t)(kt * 64 + k) * 256 + dt * 64 + c0;
        *(uint4*)(rowp) = *(uint4*)(hi);
        *(uint4*)(rowp + 8) = *(uint4*)(hi + 8);
        float* rowpf = eTf + (size_t)(kt * 64 + k) * 256 + dt * 64 + c0;
#pragma unroll
        for (int j = 0; j < 4; ++j) *(float4*)(rowpf + j * 4) = *(float4*)(fv + j * 4);
    } else {
        __shared__ float tt[64][65];
        const int b3 = bid - 544;
        const int pt = b3 & 15;          // 0..15
        const int dt = (b3 >> 4) & 3;    // 0..3
        const int b  = b3 >> 6;          // 0..31
        const float* zp = z + (size_t)b * (DD * HW) + (size_t)(dt * 64) * HW + pt * 64;
        {
            int p = t & 63, d0 = t >> 6;
#pragma unroll
            for (int j = 0; j < 16; ++j) tt[d0 + j * 4][p] = zp[(size_t)(d0 + j * 4) * HW + p];
        }
        __syncthreads();
        int p = t >> 2, c0 = (t & 3) * 16;
        int n = b * HW + pt * 64 + p;
        u16 hi[16];
#pragma unroll
        for (int j = 0; j < 16; ++j) hi[j] = rne_bf16(tt[c0 + j][p]);
        u16* rowp = A + (size_t)n * 256 + dt * 64 + c0;
        *(uint4*)(rowp) = *(uint4*)(hi);
        *(uint4*)(rowp + 8) = *(uint4*)(hi + 8);
    }
}

// ---------------- main: 512-thread, A-resident, B kit-dbuf pipelined MFMA argmin ----------------
// 8 waves = 4 M-groups x 2 N-groups. Wave tile 64 rows x 128 cols (mi=4, ni=8) at 16x16x32:
// 12 ds_read_b128 per 32 MFMA -> LDS pipe ~80% of matrix pipe (vs 125% in old mi=2 layout).
// LDS layout (both A and B): 64-B rows of 4 slots, physical slot = logical_k_chunk ^ (row&3)
// -> uniform 8 dwords/bank on ds_read_b128 (conflict-free), staged with pre-swizzled global src.
// Steady loop: stage-next-kit -> compute-current -> __syncthreads (single drain, latency hidden).
// nt0: A staged kit-interleaved under counted vmcnt(2) so the 128KB A load hides under compute.

#define STAGE_A(kit)                                                              \
    do {                                                                          \
        const u16* as_ = asrc + (kit) * 32;                                       \
        glds16(as_,             &Ast[(kit) * 8192 + w * 512]);                    \
        glds16(as_ + 128 * 256, &Ast[(kit) * 8192 + (8 + w) * 512]);              \
    } while (0)

#define STAGE_B(eoff, buf)                                                        \
    do {                                                                          \
        const u16* bs_ = bsrc0 + (eoff);                                          \
        glds16(bs_,             &Bst[buf][w * 512]);                              \
        glds16(bs_ + 128 * 256, &Bst[buf][(8 + w) * 512]);                        \
    } while (0)

#define COMPUTE_KIT(kit, first)                                                   \
    do {                                                                          \
        bf16x8 af[4], bfr[8];                                                     \
        const u16* bq_ = &Bst[(kit) & 1][0];                                      \
        _Pragma("unroll")                                                         \
        for (int mi = 0; mi < 4; ++mi)                                            \
            af[mi] = *(const bf16x8*)&Ast[(kit) * 8192 + aoff + mi * 512];        \
        _Pragma("unroll")                                                         \
        for (int ni = 0; ni < 8; ++ni)                                            \
            bfr[ni] = *(const bf16x8*)&bq_[boff + ni * 512];                      \
        __builtin_amdgcn_s_setprio(1);                                            \
        _Pragma("unroll")                                                         \
        for (int mi = 0; mi < 4; ++mi)                                            \
            _Pragma("unroll")                                                     \
            for (int ni = 0; ni < 8; ++ni)                                        \
                acc[mi][ni] = __builtin_amdgcn_mfma_f32_16x16x32_bf16(            \
                    af[mi], bfr[ni], (first) ? zacc : acc[mi][ni], 0, 0, 0);      \
        __builtin_amdgcn_s_setprio(0);                                            \
    } while (0)

__launch_bounds__(512, 2)
__global__ void argmin_mfma_kernel(const u16* __restrict__ A,   // [32768][256]
                                   const u16* __restrict__ eT,  // [8192][256]
                                   const float* __restrict__ e2f,
                                   int* __restrict__ keys) {    // [3][2][NP]
    __shared__ __align__(16) u16 Ast[8 * 8192];   // 128 KB: [kit 8][row 256][slot 4][8]
    __shared__ __align__(16) u16 Bst[2][8192];    // 2x16 KB: [col 256][slot 4][8]

    const int t = threadIdx.x;
    const int w = t >> 6;        // wave 0..7
    const int l = t & 63;
    const int wm = w & 3;        // M-group 0..3 (64 rows each)
    const int wn = w >> 2;       // N-group 0..1 (128 cols each)
    const int fr = l & 15;
    const int g  = l >> 4;

    const int split = blockIdx.x & 1;           // XCD parity -> each XCD streams one eT half
    const int pxt   = blockIdx.x >> 1;          // 0..127
    const int px0 = pxt * BROW;
    const int kb0 = split * KSPLIT;

    // staging source lane constants (pre-swizzled global source, linear LDS dest)
    const int srow = l >> 2;
    const int ssw  = ((l & 3) ^ ((l >> 2) & 3)) * 8;
    const u16* asrc  = A  + (size_t)(px0 + w * 16 + srow) * 256 + ssw;
    const u16* bsrc0 = eT + (size_t)(w * 16 + srow) * 256 + ssw;

    // fragment-read lane constants (element offsets); row&3 == fr&3 for our tiles
    const int fsw  = (g ^ (fr & 3)) * 8;
    const int aoff = (wm * 64 + fr) * 32 + fsw;    // + kit*8192 + mi*512
    const int boff = (wn * 128 + fr) * 32 + fsw;   // + ni*512

    const f32x4 zacc = (f32x4){0.f, 0.f, 0.f, 0.f};
    f32x4 acc[4][8];
    int b1[16], b2[16];
#pragma unroll
    for (int i = 0; i < 16; ++i) { b1[i] = 0x7FFFFFFF; b2[i] = 0x7FFFFFFF; }

    auto epilogue = [&](int n0) {
        float e2c[8];
        int   kc8[8];
#pragma unroll
        for (int ni = 0; ni < 8; ++ni) {
            kc8[ni] = n0 + wn * 128 + ni * 16 + fr;
            e2c[ni] = e2f[kc8[ni]] * 256.f;
        }
#pragma unroll
        for (int mi = 0; mi < 4; ++mi)
#pragma unroll
            for (int r = 0; r < 4; ++r) {
                int ky[8];
#pragma unroll
                for (int ni = 0; ni < 8; ++ni) {
                    float d = fmaf(acc[mi][ni][r], -512.f, e2c[ni]);
                    ky[ni] = (int)d * 8192 + kc8[ni];
                }
                int m0 = min(min(ky[0], ky[1]), ky[2]);
                int m1 = min(min(ky[3], ky[4]), ky[5]);
                int m2 = min(min(ky[6], ky[7]), m0);
                int kmin = min(m1, m2);
                int s = mi * 4 + r;
                int v1 = min(b1[s], kmin);
                int x  = max(b1[s], kmin);
                b2[s] = min(b2[s], x);
                b1[s] = v1;
            }
    };

    // ---- prologue: A-k0, B(nt0,k0), A-k1; wait A-k0+B-k0, keep A-k1 in flight ----
    STAGE_A(0);
    STAGE_B((size_t)kb0 * 256, 0);
    STAGE_A(1);
    asm volatile("s_waitcnt vmcnt(2)" ::: "memory");
    __builtin_amdgcn_s_barrier();

    // ---- nt0: B kit-dbuf + A kit-interleave under counted vmcnt ----
#pragma unroll
    for (int kit = 0; kit < 8; ++kit) {
        if (kit < 7) STAGE_B((size_t)kb0 * 256 + (kit + 1) * 32, (kit + 1) & 1);
        else         STAGE_B(((size_t)kb0 + BCOL) * 256, 0);        // (nt1, k0)
        if (kit < 6) STAGE_A(kit + 2);
        COMPUTE_KIT(kit, kit == 0);
        if (kit < 6) { asm volatile("s_waitcnt vmcnt(2)" ::: "memory"); }
        else         { asm volatile("s_waitcnt vmcnt(0)" ::: "memory"); }
        __builtin_amdgcn_s_barrier();
    }
    epilogue(kb0);

    // ---- steady tiles: stage-next / compute-current / single-drain barrier ----
    for (int nt = 1; nt < NTILES; ++nt) {
        const int n0 = kb0 + nt * BCOL;
#pragma unroll
        for (int kit = 0; kit < 8; ++kit) {
            if (kit < 7)
                STAGE_B((size_t)n0 * 256 + (kit + 1) * 32, (kit + 1) & 1);
            else if (nt < NTILES - 1)
                STAGE_B(((size_t)n0 + BCOL) * 256, 0);
            COMPUTE_KIT(kit, kit == 0);
            __syncthreads();
        }
        epilogue(n0);
    }

    // ---- per-wave 16-lane top-3 tree, then cross-wn merge via LDS overlay ----
    int* mrg = (int*)&Bst[0][0];   // 2*256*3 ints = 6 KB, Bst is dead now
#pragma unroll
    for (int s = 0; s < 16; ++s) {
        int c1 = b1[s], c2 = b2[s], c3 = 0x7FFFFFFF;
#pragma unroll
        for (int m = 1; m < 16; m <<= 1) {
            int a1 = __shfl_xor(c1, m, 64);
            int a2 = __shfl_xor(c2, m, 64);
            int a3 = __shfl_xor(c3, m, 64);
            int m1 = min(c1, a1);
            int xx = max(c1, a1);
            int mn2 = min(c2, a2);
            int m2 = min(xx, mn2);
            int m3 = min(min(max(c2, a2), max(xx, mn2)), min(c3, a3));
            c1 = m1; c2 = m2; c3 = m3;
        }
        if (fr == 0) {
            int row = wm * 64 + (s >> 2) * 16 + g * 4 + (s & 3);
            int o = (wn * 256 + row) * 3;
            mrg[o] = c1; mrg[o + 1] = c2; mrg[o + 2] = c3;
        }
    }
    __syncthreads();
    if (t < 256) {
        int a1 = mrg[t * 3], a2 = mrg[t * 3 + 1], a3 = mrg[t * 3 + 2];
        int u1 = mrg[(256 + t) * 3], u2 = mrg[(256 + t) * 3 + 1], u3 = mrg[(256 + t) * 3 + 2];
        int x1 = min(a1, u1), y1 = max(a1, u1);
        int n2 = min(a2, u2), M2 = max(a2, u2);
        int c1 = x1;
        int c2 = min(y1, n2);
        int c3 = min(max(y1, n2), min(M2, min(a3, u3)));
        int row = px0 + t;
        keys[split * NP + row]       = c1;
        keys[(2 + split) * NP + row] = c2;
        keys[(4 + split) * NP + row] = c3;
    }
}

// -------- finalize (fast-ws): dots + select + gather + out + loss, one pass (unchanged) --------
__global__ void finalize_kernel(const int* __restrict__ keys,
                                const float* __restrict__ z,
                                const float* __restrict__ eTf,
                                const float* __restrict__ e2f,
                                float* __restrict__ out,
                                float* __restrict__ loss) {
    __shared__ float smem[DD * 65];   // phase 1: zt[d*65+p]; phase 2: qt[p*257+d]
    __shared__ int   kc[384];
    __shared__ float dval[384];
    __shared__ int   kidx[64];
    const int t = threadIdx.x;
    const int n0 = blockIdx.x * 64;
    const float* zp = z + (size_t)(n0 >> 10) * (DD * HW) + (n0 & (HW - 1));

    for (int i = t; i < DD * 64; i += 256) {
        int d = i >> 6, p = i & 63;
        smem[d * 65 + p] = zp[(size_t)d * HW + p];   // coalesced
    }
    for (int i = t; i < 384; i += 256)
        kc[i] = keys[(i % 6) * NP + n0 + i / 6] & 8191;
    __syncthreads();

    const int l = t & 63, w = t >> 6;
    const int j = l & 15;   // lane within 16-lane dot group
    const int s = l >> 4;   // dot-group id within wave
#pragma unroll 2
    for (int it = 0; it < 24; ++it) {
        int dot = it * 16 + w * 4 + s;      // 0..383
        int p = dot / 6;
        int k = kc[dot];
        const float* er = eTf + (size_t)k * 256;
        float a = 0.f;
#pragma unroll
        for (int cc = 0; cc < 16; ++cc)
            a = fmaf(smem[(cc * 16 + j) * 65 + p], er[cc * 16 + j], a);
        a += __shfl_xor(a, 1, 64);
        a += __shfl_xor(a, 2, 64);
        a += __shfl_xor(a, 4, 64);
        a += __shfl_xor(a, 8, 64);
        if (j == 0) dval[dot] = fmaf(-2.f, a, e2f[k]);
    }
    __syncthreads();
    if (t < 64) {
        float bv = dval[t * 6];
        int   bk = kc[t * 6];
#pragma unroll
        for (int c = 1; c < 6; ++c) {
            float dv = dval[t * 6 + c];
            int   kk = kc[t * 6 + c];
            if (dv < bv || (dv == bv && kk < bk)) { bv = dv; bk = kk; }
        }
        kidx[t] = bk;
    }
    __syncthreads();

    // phase 2: bounce the 64 winning eTf rows through smem (zt is dead)
    float* qt = smem;                 // [p][d] pad 257 (257%32==1: conflict-free)
    for (int m = 0; m < 64; ++m)      // row m: 256 threads read the 1 KB row
        qt[m * 257 + t] = eTf[(size_t)kidx[m] * 256 + t];
    __syncthreads();

    const int p = t & 63, q = t >> 6;
    const size_t base = (size_t)(n0 >> 10) * (DD * HW) + (n0 & (HW - 1)) + p;
    float acc = 0.f;
#pragma unroll 8
    for (int i = 0; i < 64; ++i) {
        int d = q * 64 + i;
        float ev = qt[p * 257 + d];
        float zv = z[base + (size_t)d * HW];   // coalesced, L2-hot re-read
        out[base + (size_t)d * HW] = zv + (ev - zv);
        float df = ev - zv;
        acc = fmaf(df, df, acc);
    }
#pragma unroll
    for (int off = 32; off > 0; off >>= 1) acc += __shfl_down(acc, off, 64);
    __shared__ float part[4];
    if ((t & 63) == 0) part[t >> 6] = acc;
    __syncthreads();
    if (t == 0) {
        float s2 = (part[0] + part[1] + part[2] + part[3]) * (1.25f / 8388608.f);
        atomicAdd(loss, s2);
    }
}

// -------- slow-ws path: R7-proven separate combine + gather (unchanged) --------
__global__ void combine_kernel(const int* __restrict__ keys,
                               const float* __restrict__ z,
                               const float* __restrict__ eTf,
                               const float* __restrict__ e2f,
                               int* __restrict__ idx) {
    __shared__ float zt[DD * 65];
    __shared__ int   kc[384];
    __shared__ float dval[384];
    const int t = threadIdx.x;
    const int n0 = blockIdx.x * 64;
    const float* zp = z + (size_t)(n0 >> 10) * (DD * HW) + (n0 & (HW - 1));
    for (int i = t; i < DD * 64; i += 256) {
        int d = i >> 6, p = i & 63;
        zt[d * 65 + p] = zp[(size_t)d * HW + p];
    }
    for (int i = t; i < 384; i += 256)
        kc[i] = keys[(i % 6) * NP + n0 + i / 6] & 8191;
    __syncthreads();

    const int l = t & 63, w = t >> 6;
    const int j = l & 15;
    const int s = l >> 4;
#pragma unroll 2
    for (int it = 0; it < 24; ++it) {
        int dot = it * 16 + w * 4 + s;
        int p = dot / 6;
        int k = kc[dot];
        const float* er = eTf + (size_t)k * 256;
        float a = 0.f;
#pragma unroll
        for (int cc = 0; cc < 16; ++cc)
            a = fmaf(zt[(cc * 16 + j) * 65 + p], er[cc * 16 + j], a);
        a += __shfl_xor(a, 1, 64);
        a += __shfl_xor(a, 2, 64);
        a += __shfl_xor(a, 4, 64);
        a += __shfl_xor(a, 8, 64);
        if (j == 0) dval[dot] = fmaf(-2.f, a, e2f[k]);
    }
    __syncthreads();
    if (t < 64) {
        float bv = dval[t * 6];
        int   bk = kc[t * 6];
#pragma unroll
        for (int c = 1; c < 6; ++c) {
            float dv = dval[t * 6 + c];
            int   kk = kc[t * 6 + c];
            if (dv < bv || (dv == bv && kk < bk)) { bv = dv; bk = kk; }
        }
        idx[n0 + t] = bk;
    }
}

__global__ void gather_slow_kernel(const float* __restrict__ z,
                                   const float* __restrict__ e,
                                   const int* __restrict__ idx,
                                   float* __restrict__ out,
                                   float* __restrict__ loss) {
    const int t = threadIdx.x;
    const int n0 = blockIdx.x * 64;
    __shared__ int kidx[64];
    if (t < 64) kidx[t] = idx[n0 + t];
    __syncthreads();

    const int p = t & 63;
    const int d0 = t >> 6;
    const size_t base = (size_t)(n0 >> 10) * (DD * HW) + (n0 & (HW - 1)) + p;
    const int kk = kidx[p];

    float acc = 0.f;
    for (int d = d0; d < DD; d += 4) {
        float ev = e[(size_t)d * KN + kk];
        float zv = z[base + (size_t)d * HW];
        out[base + (size_t)d * HW] = zv + (ev - zv);
        float df = ev - zv;
        acc = fmaf(df, df, acc);
    }
#pragma unroll
    for (int off = 32; off > 0; off >>= 1) acc += __shfl_down(acc, off, 64);
    __shared__ float part[4];
    if ((t & 63) == 0) part[t >> 6] = acc;
    __syncthreads();
    if (t == 0) {
        float s = (part[0] + part[1] + part[2] + part[3]) * (1.25f / 8388608.f);
        atomicAdd(loss, s);
    }
}

extern "C" void kernel_launch(void* const* d_in, const int* in_sizes, int n_in,
                              void* d_out, int out_size, void* d_ws, size_t ws_size,
                              hipStream_t stream) {
    const float* z = (const float*)d_in[0];   // [32,256,32,32] fp32
    const float* e = (const float*)d_in[1];   // [256,8192] fp32
    float* out = (float*)d_out;
    float* loss = out + (size_t)NP * DD;      // element 8388608

    char* ob = (char*)d_out;
    char* ws = (char*)d_ws;
    u16* Acat = (u16*)ob;                            // [0, 16Mi) — consumed by argmin
    u16* eT   = (u16*)(ob + ((size_t)16 << 20));     // [16Mi, 20Mi) — consumed by argmin

    float* e2f = (float*)ws;                         // 32 KB (proven-safe region)
    int*   idx = (int*)(ws + (32 << 10));            // 128 KB
    int*   keys;
    float* eTf;
    const bool fastws = ws_size >= ((size_t)10 << 20);
    if (fastws) {
        keys = (int*)(ws + (160 << 10));             // 768 KB @ 160K
        eTf  = (float*)(ws + ((size_t)1 << 20));     // 8 MB @ 1M
    } else {
        keys = (int*)(ob + ((size_t)20 << 20));      // d_out scratch (R6-proven)
        eTf  = (float*)(ob + ((size_t)23 << 20));
    }

    prep_kernel<<<2592, 256, 0, stream>>>(e, z, eT, eTf, e2f, Acat);
    argmin_mfma_kernel<<<SPLITS * (NP / BROW), 512, 0, stream>>>(Acat, eT, e2f, keys);
    hipMemsetAsync(loss, 0, sizeof(float), stream);
    if (fastws) {
        finalize_kernel<<<NP / 64, 256, 0, stream>>>(keys, z, eTf, e2f, out, loss);
    } else {
        combine_kernel<<<NP / 64, 256, 0, stream>>>(keys, z, eTf, e2f, idx);
        gather_slow_kernel<<<NP / 64, 256, 0, stream>>>(z, e, idx, out, loss);
    }
}